// Round 13
// baseline (27.540 us; speedup 1.0000x reference)
//
#include <hip/hip_runtime.h>

// GCNConv, full upper-tri graph + self loops, B=512, N=64, C=O=256.
// out[b,i,:] = relu( (1/sqrt(i+1)) * sum_{j<=i} (X[b]W)[j,:]/sqrt(j+1) + bias )
//
// R14: async DMA staging. X staged f32 via global_load_lds width=16 (no VGPR
// round-trip, no staging VALU); source pre-swizzled (elem ^= (row&7)<<2, 16B
// granule) so swizzled ds_read_b128 is conflict-free; f32->bf16 conversion
// moved into the MFMA loop (idle VALU slack). Counted-vmcnt barriers now
// exactly expressible: W(16 loads, first) -> g0 DMA(8) -> g1 DMA(8);
// vmcnt(8)+barrier starts gemm g0 with g1 still flying; vmcnt(0) before the
// epilogue; lgkm-only barrier into gemm g1 (stores never drained).

#define BATCH 512
#define NNODE 64
#define CIN   256
#define COUT  256

typedef __bf16 bf16x8 __attribute__((ext_vector_type(8)));
typedef float  f32x4  __attribute__((ext_vector_type(4)));

__device__ __forceinline__ unsigned int f2bf_bits(float f) {
    unsigned int u = __builtin_bit_cast(unsigned int, f);
    return (u + 0x7fffu + ((u >> 16) & 1u)) >> 16;
}

// async global->LDS DMA, 16B per lane; LDS dest is wave-uniform base + lane*16
__device__ __forceinline__ void dma16(const float* g, float* l) {
    __builtin_amdgcn_global_load_lds(
        (const __attribute__((address_space(1))) unsigned int*)g,
        (__attribute__((address_space(3))) unsigned int*)l,
        16, 0, 0);
}

__global__ __launch_bounds__(512, 1) void gcn_fused(
    const float* __restrict__ X,
    const unsigned short* __restrict__ WT,   // bf16 bits, [COUT][CIN] (wprep)
    const float* __restrict__ bias,
    float* __restrict__ out)
{
    __shared__ float Xs[2][NNODE * CIN];     // 2 x 64 KB f32, source-swizzled
    const int tid  = threadIdx.x;
    const int lane = tid & 63;
    const int w    = tid >> 6;               // wave 0..7: cols [w*32, w*32+32)
    const int g    = lane >> 4;
    const int c    = lane & 15;
    const int colbase = w * 32;
    const int xg   = blockIdx.x * 2;

    const float* xb0 = X + (size_t)xg * (NNODE * CIN);
    const float* xb1 = xb0 + NNODE * CIN;

    // ---- 1) W fragments FIRST: 16 vector loads (L2), oldest in the ledger.
    // Loads land directly as bfr values (wprep pre-transposed/converted). ----
    bf16x8 bfr[8][2];                        // 64 VGPR
    {
        const unsigned short* WTb = WT + (size_t)(colbase + c) * CIN + g * 8;
#pragma unroll
        for (int kk = 0; kk < 8; ++kk)
#pragma unroll
            for (int nt = 0; nt < 2; ++nt)
                bfr[kk][nt] = *reinterpret_cast<const bf16x8*>(WTb + nt * 16 * CIN + kk * 32);
    }

    // ---- 2) async DMA: g0 rows then g1 rows (8 each; wave w stages rows
    // w*8..w*8+7). Source elem offset pre-swizzled: ^ (row&7)<<2 (16B granule);
    // LDS written linearly -> LDS[row][e^sw] holds X[row][e]. ----
    const int w8 = w * 8;
#pragma unroll
    for (int j = 0; j < 8; ++j) {
        int r = w8 + j;
        dma16(xb0 + r * 256 + ((lane * 4) ^ ((r & 7) << 2)), &Xs[0][r * 256]);
    }
#pragma unroll
    for (int j = 0; j < 8; ++j) {
        int r = w8 + j;
        dma16(xb1 + r * 256 + ((lane * 4) ^ ((r & 7) << 2)), &Xs[1][r * 256]);
    }

    float bias_c[2];
#pragma unroll
    for (int nt = 0; nt < 2; ++nt)
        bias_c[nt] = bias[colbase + nt * 16 + c];

    float dd[4][4];                          // 1/sqrt(row+1) table
#pragma unroll
    for (int mt = 0; mt < 4; ++mt)
#pragma unroll
        for (int r = 0; r < 4; ++r)
            dd[mt][r] = rsqrtf((float)(mt * 16 + g * 4 + r + 1));

    // gemm over LDS buffer s: swizzled f32 ds_read_b128 x2 + bf16 cvt + MFMA
    auto gemm = [&](int s, f32x4 (&acc)[4][2]) {
        const int sw = (c & 7) << 2;         // (row&7)==(c&7) since mt*16%8==0
#pragma unroll
        for (int kk = 0; kk < 8; ++kk) {
            bf16x8 a[4];
#pragma unroll
            for (int mt = 0; mt < 4; ++mt) {
                int row = mt * 16 + c;
                int x0  = kk * 32 + g * 8;
                f32x4 lo = *reinterpret_cast<const f32x4*>(&Xs[s][row * 256 + (x0 ^ sw)]);
                f32x4 hi = *reinterpret_cast<const f32x4*>(&Xs[s][row * 256 + ((x0 + 4) ^ sw)]);
                bf16x8 t;
                t[0] = (__bf16)lo[0]; t[1] = (__bf16)lo[1];
                t[2] = (__bf16)lo[2]; t[3] = (__bf16)lo[3];
                t[4] = (__bf16)hi[0]; t[5] = (__bf16)hi[1];
                t[6] = (__bf16)hi[2]; t[7] = (__bf16)hi[3];
                a[mt] = t;
            }
#pragma unroll
            for (int mt = 0; mt < 4; ++mt)
#pragma unroll
                for (int nt = 0; nt < 2; ++nt)
                    acc[mt][nt] = __builtin_amdgcn_mfma_f32_16x16x32_bf16(
                        a[mt], bfr[kk][nt], acc[mt][nt], 0, 0, 0);
        }
    };

    auto epilogue = [&](f32x4 (&acc)[4][2], float* ob) {
        float t_[4][2];
#pragma unroll
        for (int mt = 0; mt < 4; ++mt)
#pragma unroll
            for (int nt = 0; nt < 2; ++nt) {
                f32x4 v = acc[mt][nt];
                v[0] *= dd[mt][0]; v[1] *= dd[mt][1];
                v[2] *= dd[mt][2]; v[3] *= dd[mt][3];
                v[1] += v[0]; v[2] += v[1]; v[3] += v[2];
                acc[mt][nt] = v;
                t_[mt][nt] = v[3];
            }
        float Ofs[4][2];
#pragma unroll
        for (int nt = 0; nt < 2; ++nt) {
            float run = 0.0f;
#pragma unroll
            for (int mt = 0; mt < 4; ++mt) {
                float v    = t_[mt][nt];
                float p    = __shfl_xor(v, 16, 64);
                float excl = (g & 1) ? p : 0.0f;
                float pair = v + p;
                float q    = __shfl_xor(pair, 32, 64);
                excl += (g & 2) ? q : 0.0f;
                Ofs[mt][nt] = run + excl;
                run += pair + q;
            }
        }
#pragma unroll
        for (int mt = 0; mt < 4; ++mt)
#pragma unroll
            for (int r = 0; r < 4; ++r) {
                const int row = mt * 16 + g * 4 + r;
                const float dr = dd[mt][r];
#pragma unroll
                for (int nt = 0; nt < 2; ++nt) {
                    float val = (acc[mt][nt][r] + Ofs[mt][nt]) * dr + bias_c[nt];
                    ob[row * COUT + nt * 16] = fmaxf(val, 0.0f);
                }
            }
    };

    // ---- barrier 1: own W(16)+g0(8) retired (vmcnt<=8); g1 DMAs stay in
    // flight. Barrier then guarantees ALL waves' g0 rows are in LDS. ----
    asm volatile("s_waitcnt vmcnt(8)\n\ts_barrier" ::: "memory");
    __builtin_amdgcn_sched_barrier(0);

    f32x4 acc0[4][2] = {};
    gemm(0, acc0);

    // ---- g1 DMAs retired (they streamed under gemm g0) ----
    asm volatile("s_waitcnt vmcnt(0)" ::: "memory");

    // ---- g0 epilogue: stores issue and fly; never drained below ----
    epilogue(acc0, out + (size_t)xg * (NNODE * COUT) + colbase + c);

    // ---- barrier 2: lgkm-only; all waves' vmcnt(0) above + this barrier
    // make every g1 row visible; g0 stores keep draining underneath ----
    asm volatile("s_waitcnt lgkmcnt(0)\n\ts_barrier" ::: "memory");
    __builtin_amdgcn_sched_barrier(0);

    f32x4 acc1[4][2] = {};
    gemm(1, acc1);
    epilogue(acc1, out + (size_t)(xg + 1) * (NNODE * COUT) + colbase + c);
}

// W (f32, [K=256][N=256]) -> Wt (bf16 bits, [N=256][K=256])
__global__ void wprep(const float* __restrict__ W, unsigned short* __restrict__ Wt) {
    __shared__ unsigned short tile[64][72];
    const int tid = threadIdx.x;
    const int tk  = blockIdx.x & 3;
    const int tn  = blockIdx.x >> 2;
#pragma unroll
    for (int i = 0; i < 16; ++i) {
        int idx = tid + i * 256;
        int r  = idx >> 6;
        int cc = idx & 63;
        tile[cc][r] = (unsigned short)f2bf_bits(W[(tk * 64 + r) * 256 + tn * 64 + cc]);
    }
    __syncthreads();
#pragma unroll
    for (int i = 0; i < 16; ++i) {
        int idx = tid + i * 256;
        int rr = idx >> 6;
        int cc = idx & 63;
        Wt[(tn * 64 + rr) * 256 + tk * 64 + cc] = tile[rr][cc];
    }
}

extern "C" void kernel_launch(void* const* d_in, const int* in_sizes, int n_in,
                              void* d_out, int out_size, void* d_ws, size_t ws_size,
                              hipStream_t stream) {
    const float* x = (const float*)d_in[0];
    const float* W = (const float*)d_in[1];
    const float* bsp = (const float*)d_in[2];
    float* out = (float*)d_out;
    unsigned short* Wt = (unsigned short*)d_ws;

    hipLaunchKernelGGL(wprep, dim3(16), dim3(256), 0, stream, W, Wt);
    hipLaunchKernelGGL(gcn_fused, dim3(BATCH / 2), dim3(512), 0, stream,
                       x, Wt, bsp, out);
}